// Round 8
// baseline (99.021 us; speedup 1.0000x reference)
//
#include <hip/hip_runtime.h>
#include <stdint.h>

#define N 4096
#define BM 256
#define BK 64
#define TILES 16
#define NITEMS 260   // sum over bi of (16-bi)*ceil((bi+1)/4)
#define NWORKERS 256 // 1 block/CU (128KB LDS)
#define CHUNK 16     // k64-steps per item (K-span 1024)

typedef __attribute__((ext_vector_type(8))) short s16x8;
typedef __attribute__((ext_vector_type(4))) float f32x4;

// round-to-nearest-even fp32 -> bf16
__device__ __forceinline__ unsigned short f2bf(float f) {
  union { float f; unsigned int u; } c; c.f = f;
  unsigned int u = c.u;
  unsigned int r = (u + 0x7fffu + ((u >> 16) & 1u)) >> 16;
  return (unsigned short)r;
}

__device__ __forceinline__ void gld16(const void* g, void* l) {
  __builtin_amdgcn_global_load_lds(
      (const __attribute__((address_space(1))) unsigned int*)g,
      (__attribute__((address_space(3))) unsigned int*)l,
      16, 0, 0);
}

// Fused prepass. Order keeps Abf/Bt freshest in L3:
//  [0,12288):      C rows [1024,4096) zeroed (atomic targets, bi>=4)
//  [12288,12672):  C lower tiles (1,0)(2,0)(2,1)(3,0)(3,1)(3,2) zeroed
//  [12672,16768):  B -> triu-masked bf16 transposed (256-granular k-bound)
//  [16768,24960):  A -> tril-masked bf16 (256-granular k-bound)
__global__ void prep(const float* __restrict__ A, const float* __restrict__ B,
                     unsigned short* __restrict__ Abf, unsigned short* __restrict__ Bt,
                     float* __restrict__ C, int* __restrict__ cnt) {
  int bid = blockIdx.x;
  int t = threadIdx.x;
  if (bid == 0 && t == 0) *cnt = 0;   // prep completes before trigemm starts (stream order)
  if (bid < 12288) {
    long idx = (long)bid * 256 + t;
    float4 z = make_float4(0.f, 0.f, 0.f, 0.f);
    *reinterpret_cast<float4*>(C + (long)1024 * N + idx * 4) = z;
  } else if (bid < 12672) {
    int idx = bid - 12288;
    int tl = idx >> 6, sub = idx & 63;
    int bi = 1 + (tl >= 1) + (tl >= 3);
    int bj = tl - ((bi * bi - bi) >> 1);
    int row = bi * 256 + (sub << 2) + (t >> 6);
    int col = bj * 256 + (t & 63) * 4;
    float4 z = make_float4(0.f, 0.f, 0.f, 0.f);
    *reinterpret_cast<float4*>(C + (long)row * N + col) = z;
  } else if (bid < 16768) {
    // ---- B path: 64x64 tile transpose with triu mask ----
    int b2 = bid - 12672;
    int k0 = (b2 & 63) * 64;
    int c0 = (b2 >> 6) * 64;
    int cj = c0 >> 8;                          // 256-col tile
    if (k0 >= ((cj + 1) << 8)) return;         // never read by trigemm
    if (k0 > c0 + 63) {
      ushort4 z = make_ushort4(0, 0, 0, 0);
#pragma unroll
      for (int p = 0; p < 4; p++) {
        int cl = p * 16 + (t >> 4);
        int kl = (t & 15) * 4;
        *reinterpret_cast<ushort4*>(Bt + (long)(c0 + cl) * N + k0 + kl) = z;
      }
      return;
    }
    __shared__ unsigned short lds[64][72];     // +8 pad breaks transpose conflicts
#pragma unroll
    for (int p = 0; p < 4; p++) {
      int kl = p * 16 + (t >> 4);
      int cl = (t & 15) * 4;
      float4 v = *reinterpret_cast<const float4*>(B + (long)(k0 + kl) * N + c0 + cl);
      float vs[4] = {v.x, v.y, v.z, v.w};
#pragma unroll
      for (int i = 0; i < 4; i++)
        lds[kl][cl + i] = (k0 + kl <= c0 + cl + i) ? f2bf(vs[i]) : (unsigned short)0;
    }
    __syncthreads();
#pragma unroll
    for (int p = 0; p < 4; p++) {
      int cl = p * 16 + (t >> 4);
      int kl = (t & 15) * 4;
      ushort4 o;
      o.x = lds[kl + 0][cl]; o.y = lds[kl + 1][cl];
      o.z = lds[kl + 2][cl]; o.w = lds[kl + 3][cl];
      *reinterpret_cast<ushort4*>(Bt + (long)(c0 + cl) * N + k0 + kl) = o;
    }
  } else {
    // ---- A path: one block = half a row (2048 elems), 8 elems/thread ----
    long base = (long)(bid - 16768) * 2048 + (long)t * 8;
    int row = (int)(base >> 12);
    int k0 = (int)(base & 4095);
    int bound = ((row >> 8) + 1) << 8;         // 256-granular: first k never read
    if (k0 >= bound) return;
    if (k0 > row) {
      uint4 z = make_uint4(0u, 0u, 0u, 0u);
      *reinterpret_cast<uint4*>(Abf + base) = z;
      return;
    }
    const float4* src = reinterpret_cast<const float4*>(A + base);
    float4 v0 = src[0], v1 = src[1];
    float vs[8] = {v0.x, v0.y, v0.z, v0.w, v1.x, v1.y, v1.z, v1.w};
    unsigned int w[4];
#pragma unroll
    for (int i = 0; i < 4; i++) {
      unsigned int lo = (k0 + 2*i     <= row) ? f2bf(vs[2*i])     : 0u;
      unsigned int hi = (k0 + 2*i + 1 <= row) ? f2bf(vs[2*i + 1]) : 0u;
      w[i] = lo | (hi << 16);
    }
    uint4 o; o.x = w[0]; o.y = w[1]; o.z = w[2]; o.w = w[3];
    *reinterpret_cast<uint4*>(Abf + base) = o;
  }
}

// Triangular bf16 MFMA GEMM, 256x256 tile, 8-wave, 4-phase pipelined K-loop
// (guide SS5 8-phase template adapted), split-K over a 260-item LPT queue.
__global__ __launch_bounds__(512, 2) void trigemm(
    const unsigned short* __restrict__ Abf,
    const unsigned short* __restrict__ Bt,
    float* __restrict__ C, int* __restrict__ cnt) {
  __shared__ unsigned short lA[2][BM * BK];  // 64 KB, XOR-swizzled rows of 128B
  __shared__ unsigned short lB[2][BM * BK];  // 64 KB
  __shared__ int sh;

  int t = threadIdx.x;
  int lane = t & 63, wave = t >> 6;
  int wr = wave >> 2, wc = wave & 3;          // 2M x 4N wave grid
  int l15 = lane & 15, l4 = lane >> 4;
  int sw7 = l15 & 7;
  int c0w = (l4 ^ sw7) * 8;                   // swizzled chunk, kk=0
  int c1w = ((4 + l4) ^ sw7) * 8;             // swizzled chunk, kk=1

  // staging: thread t -> row r (0..63 within 64-row piece), 16B chunk ck
  int r = t >> 3, ck = t & 7;
  int cks = ck ^ (r & 7);                     // inverse-swizzled source chunk
  unsigned short* dA = &lA[0][0] + r * BK + ck * 8;  // linear: base + t*16B
  unsigned short* dB = &lB[0][0] + r * BK + ck * 8;

#define STA(buf, h, j, kt) gld16(gA + (long)((h)*128 + (j)*64) * N + (long)(kt) * BK, \
                                 dA + (buf) * (BM * BK) + ((h)*128 + (j)*64) * BK)
#define STB(buf, h, j, kt) gld16(gB + (long)((h)*128 + (j)*64) * N + (long)(kt) * BK, \
                                 dB + (buf) * (BM * BK) + ((h)*128 + (j)*64) * BK)
// piece order per tile: P1:{A(0,0),A(1,0)} P2:{B(0,0),B(0,1)} P3:{B(1,0),B(1,1)} P4:{A(0,1),A(1,1)}
// needed-by-P1: A*j0 + all B  -> guaranteed by vmcnt(2) at prev P4
// needed-by-P3: A*j1          -> guaranteed by vmcnt(4) at P2
#define LDA(mh, mi, kk) (*reinterpret_cast<const s16x8*>( \
    &bufA[(wr * 128 + (mh) * 64 + (mi) * 16 + l15) * BK + ((kk) ? c1w : c0w)]))
#define LDB(nh, ni, kk) (*reinterpret_cast<const s16x8*>( \
    &bufB[(wc * 64 + (nh) * 32 + (ni) * 16 + l15) * BK + ((kk) ? c1w : c0w)]))
#define MMQ(mh, nh)                                                          \
  _Pragma("unroll") for (int mi = 0; mi < 4; mi++)                           \
  _Pragma("unroll") for (int ni = 0; ni < 2; ni++)                           \
  _Pragma("unroll") for (int kk = 0; kk < 2; kk++)                           \
    acc[(mh)*4 + mi][(nh)*2 + ni] = __builtin_amdgcn_mfma_f32_16x16x32_bf16( \
        af[mi][kk], bf[ni][kk], acc[(mh)*4 + mi][(nh)*2 + ni], 0, 0, 0);

  for (;;) {
    if (t == 0) sh = atomicAdd(cnt, 1);
    __syncthreads();
    int rank = sh;
    __syncthreads();
    if (rank >= NITEMS) return;

    // rank -> (bi, bj, k-chunk): heavy-first (bi descending)
    int bi, bj, kt0 = 0;
    {
      int b_i = TILES - 1, acc2 = 0;
      for (;;) {
        int nch = (b_i + 4) >> 2;              // ceil((bi+1)/4)
        int cnt_bi = (TILES - b_i) * nch;
        if (rank < acc2 + cnt_bi) {
          int u = rank - acc2;
          int q = u / nch;
          bj = b_i + q;
          kt0 = (u - q * nch) * CHUNK;
          break;
        }
        acc2 += cnt_bi; --b_i;
      }
      bi = b_i;
    }

    int row0 = bi * BM, col0 = bj * BM;
    int nk = (bi + 1) * 4;                     // total k64-steps for this tile
    int kt1 = nk < kt0 + CHUNK ? nk : kt0 + CHUNK;
    int ns = kt1 - kt0;
    bool use_atomic = bi >= 4;

    const unsigned short* gA = Abf + (long)(row0 + r) * N + cks * 8;
    const unsigned short* gB = Bt  + (long)(col0 + r) * N + cks * 8;

    f32x4 acc[8][4];
#pragma unroll
    for (int m = 0; m < 8; m++)
#pragma unroll
      for (int n = 0; n < 4; n++)
        acc[m][n] = (f32x4){0.f, 0.f, 0.f, 0.f};

    // prologue: stage all 8 pieces of tile kt0 into buffer 0
    STA(0, 0, 0, kt0); STA(0, 1, 0, kt0);
    STB(0, 0, 0, kt0); STB(0, 0, 1, kt0); STB(0, 1, 0, kt0); STB(0, 1, 1, kt0);
    STA(0, 0, 1, kt0); STA(0, 1, 1, kt0);
    asm volatile("s_waitcnt vmcnt(2)" ::: "memory");  // P1-needed pieces done
    __builtin_amdgcn_s_barrier();

    for (int s = 0; s < ns; ++s) {
      int buf = s & 1, nb = buf ^ 1;
      bool more = (s + 1 < ns);
      int ktn = kt0 + s + 1;
      const unsigned short* bufA = &lA[buf][0];
      const unsigned short* bufB = &lB[buf][0];
      s16x8 af[4][2], bf[2][2];

      // ---- phase 1: quadrant (m0-3, n0-1) ----
#pragma unroll
      for (int mi = 0; mi < 4; mi++) { af[mi][0] = LDA(0, mi, 0); af[mi][1] = LDA(0, mi, 1); }
#pragma unroll
      for (int ni = 0; ni < 2; ni++) { bf[ni][0] = LDB(0, ni, 0); bf[ni][1] = LDB(0, ni, 1); }
      if (more) { STA(nb, 0, 0, ktn); STA(nb, 1, 0, ktn); }
      __builtin_amdgcn_s_barrier();
      __builtin_amdgcn_s_setprio(1);
      MMQ(0, 0);
      __builtin_amdgcn_s_setprio(0);
      __builtin_amdgcn_s_barrier();

      // ---- phase 2: quadrant (m0-3, n2-3) ----
#pragma unroll
      for (int ni = 0; ni < 2; ni++) { bf[ni][0] = LDB(1, ni, 0); bf[ni][1] = LDB(1, ni, 1); }
      if (more) { STB(nb, 0, 0, ktn); STB(nb, 0, 1, ktn); }
      if (more) asm volatile("s_waitcnt vmcnt(4)" ::: "memory");  // this tile's A*j1 done
      else      asm volatile("s_waitcnt vmcnt(0)" ::: "memory");
      __builtin_amdgcn_s_barrier();
      __builtin_amdgcn_s_setprio(1);
      MMQ(0, 1);
      __builtin_amdgcn_s_setprio(0);
      __builtin_amdgcn_s_barrier();

      // ---- phase 3: quadrant (m4-7, n0-1) ----
#pragma unroll
      for (int mi = 0; mi < 4; mi++) { af[mi][0] = LDA(1, mi, 0); af[mi][1] = LDA(1, mi, 1); }
#pragma unroll
      for (int ni = 0; ni < 2; ni++) { bf[ni][0] = LDB(0, ni, 0); bf[ni][1] = LDB(0, ni, 1); }
      if (more) { STB(nb, 1, 0, ktn); STB(nb, 1, 1, ktn); }
      __builtin_amdgcn_s_barrier();
      __builtin_amdgcn_s_setprio(1);
      MMQ(1, 0);
      __builtin_amdgcn_s_setprio(0);
      __builtin_amdgcn_s_barrier();

      // ---- phase 4: quadrant (m4-7, n2-3) ----
#pragma unroll
      for (int ni = 0; ni < 2; ni++) { bf[ni][0] = LDB(1, ni, 0); bf[ni][1] = LDB(1, ni, 1); }
      if (more) {
        STA(nb, 0, 1, ktn); STA(nb, 1, 1, ktn);
        asm volatile("s_waitcnt vmcnt(2)" ::: "memory");  // next tile's P1 pieces done
      }
      __builtin_amdgcn_s_barrier();
      __builtin_amdgcn_s_setprio(1);
      MMQ(1, 1);
      __builtin_amdgcn_s_setprio(0);
      __builtin_amdgcn_s_barrier();
    }

    // epilogue: C/D layout col=lane&15, row=(lane>>4)*4+reg (m89-verified)
    bool diag = (bi == bj);
#pragma unroll
    for (int m = 0; m < 8; m++) {
      int rowb = row0 + wr * 128 + m * 16 + l4 * 4;
#pragma unroll
      for (int n = 0; n < 4; n++) {
        int col = col0 + wc * 64 + n * 16 + l15;
#pragma unroll
        for (int rr = 0; rr < 4; rr++) {
          int row = rowb + rr;
          float v = acc[m][n][rr];
          if (use_atomic) {
            if (!(diag && row > col)) atomicAdd(&C[(long)row * N + col], v);
          } else {
            if (diag && row > col) v = 0.f;
            C[(long)row * N + col] = v;
          }
        }
      }
    }
  }
#undef STA
#undef STB
#undef LDA
#undef LDB
#undef MMQ
}

extern "C" void kernel_launch(void* const* d_in, const int* in_sizes, int n_in,
                              void* d_out, int out_size, void* d_ws, size_t ws_size,
                              hipStream_t stream) {
  const float* A = (const float*)d_in[0];
  const float* B = (const float*)d_in[1];
  float* C = (float*)d_out;
  unsigned short* Abf = (unsigned short*)d_ws;
  unsigned short* Bt = Abf + (size_t)N * N;
  // counter in a Bt hole: col-tile 0 only needs k<256; col=0,k=2048 never written/read
  int* cnt = (int*)(Bt + 2048);

  prep<<<dim3(24960), dim3(256), 0, stream>>>(A, B, Abf, Bt, C, cnt);
  trigemm<<<dim3(NWORKERS), dim3(512), 0, stream>>>(Abf, Bt, C, cnt);
}